// Round 6
// baseline (106.382 us; speedup 1.0000x reference)
//
#include <hip/hip_runtime.h>

#define IC 128
#define OC 256
#define RR 64
#define CCOLS 64
#define HO 62
#define WO 62
#define NB 16

// dense bf16 weights: W9T[kpos][oc][c], kpos = ky*3+kx
#define W9T_ELEMS (9 * OC * IC)
#define W9T_BYTES (W9T_ELEMS * 2)
#define LDSROW 16384   // one image row in LDS: 64 x * 256 B (128 c * bf16)

typedef __bf16 bf16x8 __attribute__((ext_vector_type(8)));
typedef float f32x4 __attribute__((ext_vector_type(4)));

__device__ __forceinline__ unsigned short f2bf(float f) {
    unsigned u = __builtin_bit_cast(unsigned, f);
    u += 0x7FFFu + ((u >> 16) & 1u);   // round-to-nearest-even
    return (unsigned short)(u >> 16);
}

__global__ void prep_weights(const float* __restrict__ wv,
                             const int* __restrict__ iwi,
                             const int* __restrict__ flen,
                             const int* __restrict__ sp,
                             unsigned short* __restrict__ W9T) {
    const int oc = blockIdx.x;
    const int s = sp[oc];
    const int n = flen[oc];
    for (int t = threadIdx.x; t < n; t += blockDim.x) {
        const int ix = iwi[s + t];          // c*4096 + ky*64 + kx
        const int c = ix >> 12;
        const int rem = ix & 4095;
        const int ky = rem >> 6, kx = rem & 63;
        W9T[((ky * 3 + kx) * OC + oc) * IC + c] = f2bf(wv[s + t]);
    }
}

__global__ void bias_kernel(const int* __restrict__ bias_index,
                            const float* __restrict__ bias_value,
                            float* __restrict__ bias_dense, int nbias) {
    int t = threadIdx.x;
    if (t < OC) bias_dense[t] = 0.f;
    __syncthreads();
    if (t < nbias) atomicAdd(&bias_dense[bias_index[t]], bias_value[t]);
}

// Block = one output row (b, y) x 128 oc (oc-half via blockIdx.y).
// 512 threads = 8 waves; wave w owns 16 oc (1 m-frag) x 64 x (4 n-tiles).
// acc = 16 AGPR, ~48 VGPR -> ~64 unified regs/wave; launch_bounds(512,6)
// caps at ~85 regs -> 6 waves/SIMD = 24 waves/CU (R5 was reg-capped at ~16
// with 88 regs/wave: MfmaUtil 15%, latency-bound).
// LDS: image rows y..y+2, x-major bf16 [3][64x][128c], XOR-swizzled (48 KB,
// 3 blocks/CU).
__global__ __launch_bounds__(512, 6) void conv_mfma(
    const float* __restrict__ images,
    const unsigned short* __restrict__ W9T,
    const float* __restrict__ bias_dense,
    float* __restrict__ out)
{
    const int y = blockIdx.x;
    const int och = blockIdx.y;         // 0..1: oc half
    const int b = blockIdx.z;
    const int t = threadIdx.x;
    const int w = t >> 6;
    const int l = t & 63;
    const int lq = l >> 4, lr = l & 15;

    __shared__ unsigned char lds[3 * LDSROW];   // 49152 B

    const float* __restrict__ imgb = images + (size_t)b * (IC * RR * CCOLS);

    // ---- stage 3 image rows, fp32 -> bf16, [x][c] with XOR swizzle ----
    // Thread t: x = t&63, channel-octet = wave id (+8 per h). ds_write_b128:
    // 8 lanes per 16B slot spread over 8 bank-groups -> minimum aliasing.
    {
        const int xs = t & 63;
        const int oct = t >> 6;             // 0..7
        const int swz = (xs & 7) << 4;
        #pragma unroll
        for (int krow = 0; krow < 3; ++krow) {
            #pragma unroll
            for (int h = 0; h < 2; ++h) {
                const int c0 = (oct + 8 * h) * 8;   // octet base channel
                const float* __restrict__ p =
                    imgb + (size_t)c0 * (RR * CCOLS) + (y + krow) * CCOLS + xs;
                unsigned v0, v1, v2, v3;
                v0 = (unsigned)f2bf(p[0])              | ((unsigned)f2bf(p[RR * CCOLS])     << 16);
                v1 = (unsigned)f2bf(p[2 * RR * CCOLS]) | ((unsigned)f2bf(p[3 * RR * CCOLS]) << 16);
                v2 = (unsigned)f2bf(p[4 * RR * CCOLS]) | ((unsigned)f2bf(p[5 * RR * CCOLS]) << 16);
                v3 = (unsigned)f2bf(p[6 * RR * CCOLS]) | ((unsigned)f2bf(p[7 * RR * CCOLS]) << 16);
                *(uint4*)(lds + krow * LDSROW + xs * 256 + ((c0 * 2) ^ swz)) =
                    make_uint4(v0, v1, v2, v3);
            }
        }
    }

    const int ocw = och * 128 + 16 * w;   // this wave's oc base
    const int cbase = 8 * lq;             // this lane's k-slice offset

    // issue first A-fragment load before the barrier (global only, no hazard)
    bf16x8 a0c = *(const bf16x8*)(W9T + (ocw + lr) * IC + cbase);

    __syncthreads();

    f32x4 acc[4] = {};

    #pragma unroll
    for (int kp = 0; kp < 9; ++kp) {
        const int ky = kp / 3, kx = kp % 3;              // compile-time
        const unsigned char* __restrict__ row = lds + ky * LDSROW;
        #pragma unroll
        for (int ci = 0; ci < 4; ++ci) {
            const int cl = ci * 32 + cbase;
            // ---- prefetch next chunk's A-fragment (double-buffer) ----
            bf16x8 a0n;
            const bool last = (kp == 8) && (ci == 3);
            if (!last) {
                const int nkp = (ci == 3) ? kp + 1 : kp;
                const int ncl = (ci == 3) ? cbase : cl + 32;
                a0n = *(const bf16x8*)(W9T + (nkp * OC + ocw + lr) * IC + ncl);
            }
            const int slot = cl * 2;
            #pragma unroll
            for (int n = 0; n < 4; ++n) {
                int x = 16 * n + lr + kx;
                x = x > 63 ? 63 : x;   // pad lanes: dup col 63 (discarded)
                const bf16x8 bf = *(const bf16x8*)(
                    row + x * 256 + (slot ^ ((x & 7) << 4)));
                acc[n] = __builtin_amdgcn_mfma_f32_16x16x32_bf16(
                    a0c, bf, acc[n], 0, 0, 0);
            }
            if (!last) a0c = a0n;
        }
    }

    // ---- epilogue: bias + store (C/D: col = lane&15, row = 4*lq + r) ----
    {
        const int ocb = ocw + 4 * lq;
        float bv[4];
        #pragma unroll
        for (int r = 0; r < 4; ++r) bv[r] = bias_dense[ocb + r];
        #pragma unroll
        for (int n = 0; n < 4; ++n) {
            const int x = 16 * n + lr;
            if (x < WO) {
                #pragma unroll
                for (int r = 0; r < 4; ++r)
                    out[(((size_t)b * OC + ocb + r) * HO + y) * WO + x] =
                        acc[n][r] + bv[r];
            }
        }
    }
}

extern "C" void kernel_launch(void* const* d_in, const int* in_sizes, int n_in,
                              void* d_out, int out_size, void* d_ws, size_t ws_size,
                              hipStream_t stream) {
    const float* images             = (const float*)d_in[0];
    const float* weight_value       = (const float*)d_in[1];
    const int*   image_weight_index = (const int*)d_in[2];
    const int*   filter_lengths     = (const int*)d_in[3];
    const int*   start_points       = (const int*)d_in[4];
    const int*   bias_index         = (const int*)d_in[5];
    const float* bias_value         = (const float*)d_in[6];
    float* out = (float*)d_out;

    unsigned short* W9T = (unsigned short*)d_ws;
    float* bias_dense = (float*)((char*)d_ws + W9T_BYTES);

    hipMemsetAsync(d_ws, 0, W9T_BYTES, stream);
    prep_weights<<<OC, 256, 0, stream>>>(weight_value, image_weight_index,
                                         filter_lengths, start_points, W9T);
    bias_kernel<<<1, 256, 0, stream>>>(bias_index, bias_value, bias_dense,
                                       in_sizes[5]);

    dim3 grid(HO, 2, NB);
    conv_mfma<<<grid, 512, 0, stream>>>(images, W9T, bias_dense, out);
}

// Round 7
// 100.669 us; speedup vs baseline: 1.0568x; 1.0568x over previous
//
#include <hip/hip_runtime.h>

#define IC 128
#define OC 256
#define RR 64
#define CCOLS 64
#define HO 62
#define WO 62
#define NB 16

// dense bf16 weights: W9T[kpos][oc][c], kpos = ky*3+kx
#define W9T_ELEMS (9 * OC * IC)
#define W9T_BYTES (W9T_ELEMS * 2)
#define LDSROW 16384   // one image row in LDS: 64 x * 256 B (128 c * bf16)

typedef __bf16 bf16x8 __attribute__((ext_vector_type(8)));
typedef float f32x16 __attribute__((ext_vector_type(16)));

__device__ __forceinline__ unsigned short f2bf(float f) {
    unsigned u = __builtin_bit_cast(unsigned, f);
    u += 0x7FFFu + ((u >> 16) & 1u);   // round-to-nearest-even
    return (unsigned short)(u >> 16);
}

__global__ void prep_weights(const float* __restrict__ wv,
                             const int* __restrict__ iwi,
                             const int* __restrict__ flen,
                             const int* __restrict__ sp,
                             unsigned short* __restrict__ W9T) {
    const int oc = blockIdx.x;
    const int s = sp[oc];
    const int n = flen[oc];
    for (int t = threadIdx.x; t < n; t += blockDim.x) {
        const int ix = iwi[s + t];          // c*4096 + ky*64 + kx
        const int c = ix >> 12;
        const int rem = ix & 4095;
        const int ky = rem >> 6, kx = rem & 63;
        W9T[((ky * 3 + kx) * OC + oc) * IC + c] = f2bf(wv[s + t]);
    }
}

__global__ void bias_kernel(const int* __restrict__ bias_index,
                            const float* __restrict__ bias_value,
                            float* __restrict__ bias_dense, int nbias) {
    int t = threadIdx.x;
    if (t < OC) bias_dense[t] = 0.f;
    __syncthreads();
    if (t < nbias) atomicAdd(&bias_dense[bias_index[t]], bias_value[t]);
}

// Block = one output row (b, y) x all 256 oc. 512 threads = 8 waves.
// Wave w: 32 oc (one 32x32 m-frag) x 64 x (2 n-tiles of 32).
// mfma_f32_32x32x16_bf16: 32 KFLOP per 16B ds_read -> 2x arithmetic
// intensity vs R6's 16x16x32 (which plateaued at MfmaUtil 15%).
// A prefetched 2 chunks deep (covers ~300cy L2 latency).
// LDS: rows y..y+2, x-major bf16 [3][64x][128c], XOR-swizzled, 48 KB.
__global__ __launch_bounds__(512, 2) void conv_mfma(
    const float* __restrict__ images,
    const unsigned short* __restrict__ W9T,
    const float* __restrict__ bias_dense,
    float* __restrict__ out)
{
    const int y = blockIdx.x;
    const int b = blockIdx.y;
    const int t = threadIdx.x;
    const int w = t >> 6;
    const int l = t & 63;
    const int lm = l & 31;            // m-row / n-col within frag
    const int lhi = l >> 5;           // k-half

    __shared__ unsigned char lds[3 * LDSROW];   // 49152 B

    const float* __restrict__ imgb = images + (size_t)b * (IC * RR * CCOLS);

    // ---- stage 3 image rows, fp32 -> bf16, [x][c] with XOR swizzle ----
    {
        const int xs = t & 63;
        const int oct = t >> 6;             // 0..7
        const int swz = (xs & 7) << 4;
        #pragma unroll
        for (int krow = 0; krow < 3; ++krow) {
            #pragma unroll
            for (int h = 0; h < 2; ++h) {
                const int c0 = (oct + 8 * h) * 8;   // octet base channel
                const float* __restrict__ p =
                    imgb + (size_t)c0 * (RR * CCOLS) + (y + krow) * CCOLS + xs;
                unsigned v0, v1, v2, v3;
                v0 = (unsigned)f2bf(p[0])              | ((unsigned)f2bf(p[RR * CCOLS])     << 16);
                v1 = (unsigned)f2bf(p[2 * RR * CCOLS]) | ((unsigned)f2bf(p[3 * RR * CCOLS]) << 16);
                v2 = (unsigned)f2bf(p[4 * RR * CCOLS]) | ((unsigned)f2bf(p[5 * RR * CCOLS]) << 16);
                v3 = (unsigned)f2bf(p[6 * RR * CCOLS]) | ((unsigned)f2bf(p[7 * RR * CCOLS]) << 16);
                *(uint4*)(lds + krow * LDSROW + xs * 256 + ((c0 * 2) ^ swz)) =
                    make_uint4(v0, v1, v2, v3);
            }
        }
    }

    const int ocw = 32 * w;
    // lane's A base: row ocw+lm, k-half offset lhi*8
    const unsigned short* __restrict__ pA = W9T + (ocw + lm) * IC + lhi * 8;

    // prologue: prefetch chunks 0,1 (global only, no LDS hazard)
    bf16x8 aC = *(const bf16x8*)(pA);
    bf16x8 aN1 = *(const bf16x8*)(pA + 16);
    bf16x8 aN2;

    __syncthreads();

    f32x16 acc[2] = {};

    #pragma unroll
    for (int kp = 0; kp < 9; ++kp) {
        const int ky = kp / 3, kx = kp % 3;              // compile-time
        // per-kp B byte-address bases (within a 16 KB LDS row)
        const int x0 = lm + kx;                          // <= 33, no clamp
        int x1 = 32 + lm + kx;
        x1 = x1 > 63 ? 63 : x1;   // pad lanes: dup col 63 (output discarded)
        const int pb0 = x0 * 256 + ((lhi * 16) ^ ((x0 & 7) << 4));
        const int pb1 = x1 * 256 + ((lhi * 16) ^ ((x1 & 7) << 4));
        const unsigned char* __restrict__ row = lds + ky * LDSROW;

        #pragma unroll
        for (int ck = 0; ck < 8; ++ck) {
            const int idx = kp * 8 + ck;
            if (idx + 2 < 72) {     // prefetch chunk idx+2 (compile-time addr)
                const int i2 = idx + 2;
                aN2 = *(const bf16x8*)(pA + (i2 >> 3) * (OC * IC) + (i2 & 7) * 16);
            }
            const bf16x8 b0 = *(const bf16x8*)(row + (pb0 ^ (ck * 32)));
            const bf16x8 b1 = *(const bf16x8*)(row + (pb1 ^ (ck * 32)));
            acc[0] = __builtin_amdgcn_mfma_f32_32x32x16_bf16(aC, b0, acc[0], 0, 0, 0);
            acc[1] = __builtin_amdgcn_mfma_f32_32x32x16_bf16(aC, b1, acc[1], 0, 0, 0);
            aC = aN1; aN1 = aN2;    // SSA-renamed after full unroll, no copies
        }
    }

    // ---- epilogue: bias + store ----
    // C/D 32x32: col = lane&31, row = (reg&3) + 8*(reg>>2) + 4*(lane>>5)
    #pragma unroll
    for (int r = 0; r < 16; ++r) {
        const int oc = ocw + (r & 3) + 8 * (r >> 2) + 4 * lhi;
        const float bv = bias_dense[oc];
        const size_t ob = (((size_t)b * OC + oc) * HO + y) * WO;
        // n = 0: x = lm <= 31 < 62, always stored
        out[ob + lm] = acc[0][r] + bv;
        // n = 1: x = 32 + lm, store if < 62
        if (lm < 30)
            out[ob + 32 + lm] = acc[1][r] + bv;
    }
}

extern "C" void kernel_launch(void* const* d_in, const int* in_sizes, int n_in,
                              void* d_out, int out_size, void* d_ws, size_t ws_size,
                              hipStream_t stream) {
    const float* images             = (const float*)d_in[0];
    const float* weight_value       = (const float*)d_in[1];
    const int*   image_weight_index = (const int*)d_in[2];
    const int*   filter_lengths     = (const int*)d_in[3];
    const int*   start_points       = (const int*)d_in[4];
    const int*   bias_index         = (const int*)d_in[5];
    const float* bias_value         = (const float*)d_in[6];
    float* out = (float*)d_out;

    unsigned short* W9T = (unsigned short*)d_ws;
    float* bias_dense = (float*)((char*)d_ws + W9T_BYTES);

    hipMemsetAsync(d_ws, 0, W9T_BYTES, stream);
    prep_weights<<<OC, 256, 0, stream>>>(weight_value, image_weight_index,
                                         filter_lengths, start_points, W9T);
    bias_kernel<<<1, 256, 0, stream>>>(bias_index, bias_value, bias_dense,
                                       in_sizes[5]);

    dim3 grid(HO, NB);
    conv_mfma<<<grid, 512, 0, stream>>>(images, W9T, bias_dense, out);
}

// Round 8
// 72.718 us; speedup vs baseline: 1.4629x; 1.3844x over previous
//
#include <hip/hip_runtime.h>

#define IC 128
#define OC 256
#define RR 64
#define CCOLS 64
#define HO 62
#define WO 62
#define NB 16

// Fragment-major dense bf16 weights:
//   W9Tf[chunk][w][lane][elem], chunk = kp*8+ck (72), w = oc>>5 (8 groups),
//   lane = (oc&31) + 32*khalf (64), elem = c&7 (8 bf16 = 16 B).
// A wave's A-fragment load for one chunk is base + lane*16: 1 KB contiguous
// (R7's [oc][c] layout was a 256B-lane-stride gather: 32 cache lines / load,
// ~70K cyc/CU of TA occupancy -> the invariant ~100 us floor of R5-R7).
#define W9T_BYTES (9 * OC * IC * 2)   // 589824
#define CHUNK_STRIDE 8192             // 8 ocgroups * 64 lanes * 16 B
#define LDSROW 16384                  // one image row: 64 x * 256 B

typedef __bf16 bf16x8 __attribute__((ext_vector_type(8)));
typedef float f32x16 __attribute__((ext_vector_type(16)));

__device__ __forceinline__ unsigned short f2bf(float f) {
    unsigned u = __builtin_bit_cast(unsigned, f);
    u += 0x7FFFu + ((u >> 16) & 1u);   // round-to-nearest-even
    return (unsigned short)(u >> 16);
}

__global__ void prep_weights(const float* __restrict__ wv,
                             const int* __restrict__ iwi,
                             const int* __restrict__ flen,
                             const int* __restrict__ sp,
                             unsigned char* __restrict__ W9Tf) {
    const int oc = blockIdx.x;
    const int s = sp[oc];
    const int n = flen[oc];
    const int w = oc >> 5;
    for (int t = threadIdx.x; t < n; t += blockDim.x) {
        const int ix = iwi[s + t];          // c*4096 + ky*64 + kx
        const int c = ix >> 12;
        const int rem = ix & 4095;
        const int ky = rem >> 6, kx = rem & 63;
        const int kp = ky * 3 + kx;
        const int ck = c >> 4;
        const int khalf = (c >> 3) & 1;
        const int lane = (oc & 31) + (khalf << 5);
        const size_t off = (size_t)(kp * 8 + ck) * CHUNK_STRIDE +
                           w * 1024 + lane * 16 + (c & 7) * 2;
        *(unsigned short*)(W9Tf + off) = f2bf(wv[s + t]);
    }
}

__global__ void bias_kernel(const int* __restrict__ bias_index,
                            const float* __restrict__ bias_value,
                            float* __restrict__ bias_dense, int nbias) {
    int t = threadIdx.x;
    if (t < OC) bias_dense[t] = 0.f;
    __syncthreads();
    if (t < nbias) atomicAdd(&bias_dense[bias_index[t]], bias_value[t]);
}

// Block = one output row (b, y) x all 256 oc. 512 threads = 8 waves.
// Wave w: 32 oc (one 32x32 m-frag) x 64 x (2 n-tiles of 32).
// A: coalesced fragment-major loads, prefetched 3 chunks deep.
// B: LDS x-major [3][64x][128c] XOR-swizzled, double-buffered 1 chunk deep.
__global__ __launch_bounds__(512, 2) void conv_mfma(
    const float* __restrict__ images,
    const unsigned char* __restrict__ W9Tf,
    const float* __restrict__ bias_dense,
    float* __restrict__ out)
{
    const int y = blockIdx.x;
    const int b = blockIdx.y;
    const int t = threadIdx.x;
    const int w = t >> 6;
    const int l = t & 63;
    const int lm = l & 31;            // m-row / n-col within frag
    const int lhi = l >> 5;           // k-half

    __shared__ unsigned char lds[3 * LDSROW];   // 49152 B

    const float* __restrict__ imgb = images + (size_t)b * (IC * RR * CCOLS);

    // ---- stage 3 image rows, fp32 -> bf16, [x][c] with XOR swizzle ----
    {
        const int xs = t & 63;
        const int oct = t >> 6;             // 0..7
        const int swz = (xs & 7) << 4;
        #pragma unroll
        for (int krow = 0; krow < 3; ++krow) {
            #pragma unroll
            for (int h = 0; h < 2; ++h) {
                const int c0 = (oct + 8 * h) * 8;   // octet base channel
                const float* __restrict__ p =
                    imgb + (size_t)c0 * (RR * CCOLS) + (y + krow) * CCOLS + xs;
                unsigned v0, v1, v2, v3;
                v0 = (unsigned)f2bf(p[0])              | ((unsigned)f2bf(p[RR * CCOLS])     << 16);
                v1 = (unsigned)f2bf(p[2 * RR * CCOLS]) | ((unsigned)f2bf(p[3 * RR * CCOLS]) << 16);
                v2 = (unsigned)f2bf(p[4 * RR * CCOLS]) | ((unsigned)f2bf(p[5 * RR * CCOLS]) << 16);
                v3 = (unsigned)f2bf(p[6 * RR * CCOLS]) | ((unsigned)f2bf(p[7 * RR * CCOLS]) << 16);
                *(uint4*)(lds + krow * LDSROW + xs * 256 + ((c0 * 2) ^ swz)) =
                    make_uint4(v0, v1, v2, v3);
            }
        }
    }

    // lane's coalesced A base
    const unsigned char* __restrict__ pA = W9Tf + w * 1024 + l * 16;

    // prologue: prefetch A chunks 0..2 (global only, no LDS hazard)
    bf16x8 aC  = *(const bf16x8*)(pA);
    bf16x8 aN1 = *(const bf16x8*)(pA + CHUNK_STRIDE);
    bf16x8 aN2 = *(const bf16x8*)(pA + 2 * CHUNK_STRIDE);

    __syncthreads();

    // B reader for chunk idx (idx, hence ky/kx/ck, compile-time under unroll)
    auto readB = [&](int idx, bf16x8& b0, bf16x8& b1) {
        const int kp = idx >> 3, ck = idx & 7;
        const int ky = kp / 3, kx = kp % 3;
        const int x0 = lm + kx;                      // <= 33, in-bounds
        int x1 = 32 + lm + kx;
        x1 = x1 > 63 ? 63 : x1;   // pad lanes: dup col 63 (output discarded)
        const unsigned char* __restrict__ row = lds + ky * LDSROW;
        const int pb0 = x0 * 256 + ((lhi * 16) ^ ((x0 & 7) << 4));
        const int pb1 = x1 * 256 + ((lhi * 16) ^ ((x1 & 7) << 4));
        b0 = *(const bf16x8*)(row + (pb0 ^ (ck * 32)));
        b1 = *(const bf16x8*)(row + (pb1 ^ (ck * 32)));
    };

    f32x16 acc0 = {}, acc1 = {};
    bf16x8 b0c, b1c;
    readB(0, b0c, b1c);

    #pragma unroll
    for (int idx = 0; idx < 72; ++idx) {
        // prefetch A chunk idx+3 (coalesced 1 KB global load)
        bf16x8 aN3;
        if (idx + 3 < 72)
            aN3 = *(const bf16x8*)(pA + (size_t)(idx + 3) * CHUNK_STRIDE);
        // prefetch B chunk idx+1 (2x ds_read_b128, covered by MFMAs below)
        bf16x8 b0n, b1n;
        if (idx + 1 < 72) readB(idx + 1, b0n, b1n);

        acc0 = __builtin_amdgcn_mfma_f32_32x32x16_bf16(aC, b0c, acc0, 0, 0, 0);
        acc1 = __builtin_amdgcn_mfma_f32_32x32x16_bf16(aC, b1c, acc1, 0, 0, 0);

        aC = aN1; aN1 = aN2; aN2 = aN3;          // SSA-renamed, no copies
        if (idx + 1 < 72) { b0c = b0n; b1c = b1n; }
    }

    // ---- epilogue: bias + store ----
    // C/D 32x32: col = lane&31, row = (reg&3) + 8*(reg>>2) + 4*(lane>>5)
    const int ocw = 32 * w;
    #pragma unroll
    for (int r = 0; r < 16; ++r) {
        const int oc = ocw + (r & 3) + 8 * (r >> 2) + 4 * lhi;
        const float bv = bias_dense[oc];
        const size_t ob = (((size_t)b * OC + oc) * HO + y) * WO;
        out[ob + lm] = acc0[r] + bv;             // x = lm < 62 always
        if (lm < 30)
            out[ob + 32 + lm] = acc1[r] + bv;    // x = 32+lm, clip at 62
    }
}

extern "C" void kernel_launch(void* const* d_in, const int* in_sizes, int n_in,
                              void* d_out, int out_size, void* d_ws, size_t ws_size,
                              hipStream_t stream) {
    const float* images             = (const float*)d_in[0];
    const float* weight_value       = (const float*)d_in[1];
    const int*   image_weight_index = (const int*)d_in[2];
    const int*   filter_lengths     = (const int*)d_in[3];
    const int*   start_points       = (const int*)d_in[4];
    const int*   bias_index         = (const int*)d_in[5];
    const float* bias_value         = (const float*)d_in[6];
    float* out = (float*)d_out;

    unsigned char* W9Tf = (unsigned char*)d_ws;
    float* bias_dense = (float*)((char*)d_ws + W9T_BYTES);

    hipMemsetAsync(d_ws, 0, W9T_BYTES, stream);
    prep_weights<<<OC, 256, 0, stream>>>(weight_value, image_weight_index,
                                         filter_lengths, start_points, W9Tf);
    bias_kernel<<<1, 256, 0, stream>>>(bias_index, bias_value, bias_dense,
                                       in_sizes[5]);

    dim3 grid(HO, NB);
    conv_mfma<<<grid, 512, 0, stream>>>(images, W9Tf, bias_dense, out);
}